// Round 10
// baseline (682.870 us; speedup 1.0000x reference)
//
#include <hip/hip_runtime.h>

#define N_NODES 100000
#define N_EDGES 2500000
#define SBBITS 11
#define SBSZ 2048              // nodes per superbucket
#define NSB 49                 // ceil(N_NODES/2048)
#define M 15                   // agg slices per superbucket
#define GRID (NSB * M)         // 735 blocks; <= 256 CUs * 3 blocks/CU = 768 co-resident
#define EPB 3402               // ceil(N_EDGES/GRID)
#define TOT (NSB * GRID)       // 36015 (k-major, block-minor counts)
#define CHK 49                 // TOT/GRID exactly

// pass-1 fixed point: (x+16)*2^16; u32 sum ok; signed debias via (int) [R6-validated]
// pass-2 fixed point: (h2+2048)*2^12; signed debias via (int)          [R6-validated]

typedef unsigned int u32;
typedef unsigned long long u64;

// One-shot grid barrier (each slot used exactly once per launch).
// __threadfence() = agent-scope fence: writes back dirty L2 / invalidates stale
// lines, required across non-coherent per-XCD L2s. atomicAdd is device-scope.
__device__ __forceinline__ void gbar(u32* bar, int slot) {
    __syncthreads();
    if (threadIdx.x == 0) {
        __threadfence();
        atomicAdd(&bar[slot], 1u);
        while (__hip_atomic_load(&bar[slot], __ATOMIC_RELAXED,
                                 __HIP_MEMORY_SCOPE_AGENT) < GRID)
            __builtin_amdgcn_s_sleep(1);
        __threadfence();
    }
    __syncthreads();
}

__global__ __launch_bounds__(256, 3) void mega(
    const float* __restrict__ x, const int* __restrict__ ei,
    const float* __restrict__ Wl1, const float* __restrict__ Wr1,
    const float* __restrict__ b1, const float* __restrict__ Wl2,
    const float* __restrict__ Wr2, const float* __restrict__ b2,
    u32* bar, u32* __restrict__ histG, u32* __restrict__ bsum,
    u32* __restrict__ sortedE, u32* __restrict__ PART, u32* __restrict__ PART2,
    u64* __restrict__ ench2, float2* __restrict__ hrG, float* __restrict__ degG,
    float* __restrict__ out)
{
    __shared__ u32 sm[3 * SBSZ];   // 24 KB, reused per phase
    const int t = threadIdx.x, b = blockIdx.x;

    // ---------------- P1: per-(sb, block) histogram ----------------
    for (int k = t; k < NSB * 8; k += 256) sm[k] = 0;
    __syncthreads();
    {
        int e0 = b * EPB, e1 = min(e0 + EPB, N_EDGES);
        int r = t & 7;
        for (int e = e0 + t; e < e1; e += 256) {
            u32 dst = (u32)ei[N_EDGES + e];
            atomicAdd(&sm[(dst >> SBBITS) * 8 + r], 1u);
        }
    }
    __syncthreads();
    for (int k = t; k < NSB; k += 256) {
        u32 s = 0;
#pragma unroll
        for (int j = 0; j < 8; ++j) s += sm[k * 8 + j];
        histG[k * GRID + b] = s;
    }
    gbar(bar, 0);

    // ---------------- P2: local scan of this block's 49-chunk ----------------
    u32 excl = 0;
    {
        u32 v = (t < CHK) ? histG[b * CHK + t] : 0u;
        if (t < 64) sm[t] = v;
        __syncthreads();
        for (int off = 1; off < 64; off <<= 1) {
            u32 a = (t >= off && t < 64) ? sm[t - off] : 0u;
            __syncthreads();
            if (t < 64) sm[t] += a;
            __syncthreads();
        }
        if (t < CHK) excl = (t == 0) ? 0u : sm[t - 1];
        if (t == 0) bsum[b] = sm[CHK - 1];
        __syncthreads();
    }
    gbar(bar, 1);

    // ---------------- P3: global base (masked sum of bsum[<b]) + writeback ----
    {
        u32 part = 0;
        for (int j = t; j < b; j += 256) part += bsum[j];
        sm[t] = part;
        __syncthreads();
        for (int off = 128; off > 0; off >>= 1) {
            if (t < off) sm[t] += sm[t + off];
            __syncthreads();
        }
        u32 base = sm[0];
        __syncthreads();
        if (t < CHK) histG[b * CHK + t] = base + excl;
    }
    gbar(bar, 2);

    // ---------------- P4: scatter into superbucket order ----------------
    {
        if (t < NSB) sm[t] = histG[t * GRID + b];
        __syncthreads();
        int e0 = b * EPB, e1 = min(e0 + EPB, N_EDGES);
        for (int e = e0 + t; e < e1; e += 256) {
            u32 src = (u32)ei[e];
            u32 dst = (u32)ei[N_EDGES + e];
            u32 slot = atomicAdd(&sm[dst >> SBBITS], 1u);
            sortedE[slot] = ((dst & (SBSZ - 1u)) << 17) | src;
        }
    }
    gbar(bar, 3);

    // ---------------- P5: agg1 (LDS fixed-point partials of x) ----------------
    {
        u32 sb = (u32)b / M, m = (u32)b % M;
        for (int j = t; j < 3 * SBSZ; j += 256) sm[j] = 0;
        __syncthreads();
        u32 s0 = histG[sb * GRID];
        u32 s1 = (sb + 1 < NSB) ? histG[(sb + 1) * GRID] : N_EDGES;
        u32 len = s1 - s0;
        u32 a0 = s0 + len * m / M, a1 = s0 + len * (m + 1) / M;
        const float2* x2 = (const float2*)x;
        u32 idx = a0 + t;
        while (idx + 256 < a1) {
            u32 p0 = sortedE[idx], p1 = sortedE[idx + 256];
            float2 v0 = x2[p0 & 0x1FFFFu];
            float2 v1 = x2[p1 & 0x1FFFFu];
            u32 l0 = p0 >> 17, l1 = p1 >> 17;
            atomicAdd(&sm[l0], 1u);
            atomicAdd(&sm[SBSZ + l0], (u32)((v0.x + 16.0f) * 65536.0f + 0.5f));
            atomicAdd(&sm[2 * SBSZ + l0], (u32)((v0.y + 16.0f) * 65536.0f + 0.5f));
            atomicAdd(&sm[l1], 1u);
            atomicAdd(&sm[SBSZ + l1], (u32)((v1.x + 16.0f) * 65536.0f + 0.5f));
            atomicAdd(&sm[2 * SBSZ + l1], (u32)((v1.y + 16.0f) * 65536.0f + 0.5f));
            idx += 512;
        }
        while (idx < a1) {
            u32 p = sortedE[idx];
            float2 v = x2[p & 0x1FFFFu];
            u32 l = p >> 17;
            atomicAdd(&sm[l], 1u);
            atomicAdd(&sm[SBSZ + l], (u32)((v.x + 16.0f) * 65536.0f + 0.5f));
            atomicAdd(&sm[2 * SBSZ + l], (u32)((v.y + 16.0f) * 65536.0f + 0.5f));
            idx += 256;
        }
        __syncthreads();
        u32 base = (u32)b * (3 * SBSZ);
        for (int j = t; j < 3 * SBSZ; j += 256) PART[base + j] = sm[j];
    }
    gbar(bar, 4);

    // ---------------- P6: reduce partials + node layer 1 ----------------
    {
        float* smf = (float*)sm;
        if (t < 64) {
            smf[t] = Wl1[t]; smf[64 + t] = Wr1[t];
            smf[128 + t] = Wl2[t]; smf[192 + t] = Wr2[t];
        }
        if (t >= 64 && t < 96) smf[256 + (t - 64)] = b1[t - 64];
        __syncthreads();
        int i = b * 137 + t;          // 735*137 = 100695 >= N
        if (t < 137 && i < N_NODES) {
            u32 sb2 = (u32)i >> SBBITS, j = (u32)i & (SBSZ - 1u);
            u32 cnt = 0, fx = 0, fy = 0;
#pragma unroll
            for (int mm = 0; mm < M; ++mm) {
                u32 bb = (sb2 * M + mm) * (3 * SBSZ);
                cnt += PART[bb + j];
                fx  += PART[bb + SBSZ + j];
                fy  += PART[bb + 2 * SBSZ + j];
            }
            float fc = (float)cnt;
            float dinv = 1.0f / fmaxf(fc, 1.0f);
            float ax = (float)(int)(fx - cnt * 1048576u) * (1.0f / 65536.0f) * dinv;
            float ay = (float)(int)(fy - cnt * 1048576u) * (1.0f / 65536.0f) * dinv;
            float2 xv = ((const float2*)x)[i];
            float h2a = 0.f, h2b = 0.f, hra = 0.f, hrb = 0.f;
#pragma unroll
            for (int f = 0; f < 32; ++f) {
                float h = ax * smf[f] + ay * smf[32 + f] +
                          xv.x * smf[64 + f] + xv.y * smf[96 + f] + smf[256 + f];
                h = fmaxf(h, 0.0f);
                h2a += h * smf[128 + 2 * f];
                h2b += h * smf[128 + 2 * f + 1];
                hra += h * smf[192 + 2 * f];
                hrb += h * smf[192 + 2 * f + 1];
            }
            u32 ex = (u32)((h2a + 2048.0f) * 4096.0f + 0.5f);
            u32 ey = (u32)((h2b + 2048.0f) * 4096.0f + 0.5f);
            ench2[i] = ((u64)ey << 32) | (u64)ex;
            hrG[i] = make_float2(hra, hrb);
            degG[i] = fc;
        }
    }
    gbar(bar, 5);

    // ---------------- P7: agg2 (LDS partials of encoded h2) ----------------
    {
        u32 sb = (u32)b / M, m = (u32)b % M;
        for (int j = t; j < 2 * SBSZ; j += 256) sm[j] = 0;
        __syncthreads();
        u32 s0 = histG[sb * GRID];
        u32 s1 = (sb + 1 < NSB) ? histG[(sb + 1) * GRID] : N_EDGES;
        u32 len = s1 - s0;
        u32 a0 = s0 + len * m / M, a1 = s0 + len * (m + 1) / M;
        u32 idx = a0 + t;
        while (idx + 256 < a1) {
            u32 p0 = sortedE[idx], p1 = sortedE[idx + 256];
            u64 e0 = ench2[p0 & 0x1FFFFu];
            u64 e1 = ench2[p1 & 0x1FFFFu];
            u32 l0 = p0 >> 17, l1 = p1 >> 17;
            atomicAdd(&sm[l0], (u32)e0);
            atomicAdd(&sm[SBSZ + l0], (u32)(e0 >> 32));
            atomicAdd(&sm[l1], (u32)e1);
            atomicAdd(&sm[SBSZ + l1], (u32)(e1 >> 32));
            idx += 512;
        }
        while (idx < a1) {
            u32 p = sortedE[idx];
            u64 e = ench2[p & 0x1FFFFu];
            u32 l = p >> 17;
            atomicAdd(&sm[l], (u32)e);
            atomicAdd(&sm[SBSZ + l], (u32)(e >> 32));
            idx += 256;
        }
        __syncthreads();
        u32 base = (u32)b * (2 * SBSZ);
        for (int j = t; j < 2 * SBSZ; j += 256) PART2[base + j] = sm[j];
    }
    gbar(bar, 6);

    // ---------------- P8: reduce + node layer 2 + log_softmax ----------------
    {
        int i = b * 137 + t;
        if (t < 137 && i < N_NODES) {
            u32 sb2 = (u32)i >> SBBITS, j = (u32)i & (SBSZ - 1u);
            u32 gx = 0, gy = 0;
#pragma unroll
            for (int mm = 0; mm < M; ++mm) {
                u32 bb = (sb2 * M + mm) * (2 * SBSZ);
                gx += PART2[bb + j];
                gy += PART2[bb + SBSZ + j];
            }
            float fc = degG[i];
            u32 c = (u32)fc;
            float dinv = 1.0f / fmaxf(fc, 1.0f);
            float sx = (float)(int)(gx - c * 8388608u) * (1.0f / 4096.0f) * dinv;
            float sy = (float)(int)(gy - c * 8388608u) * (1.0f / 4096.0f) * dinv;
            float2 hv = hrG[i];
            float o0 = sx + hv.x + b2[0];
            float o1 = sy + hv.y + b2[1];
            float mx = fmaxf(o0, o1);
            float e0 = expf(o0 - mx);
            float e1 = expf(o1 - mx);
            float lse = logf(e0 + e1);
            ((float2*)out)[i] = make_float2(o0 - mx - lse, o1 - mx - lse);
        }
    }
}

extern "C" void kernel_launch(void* const* d_in, const int* in_sizes, int n_in,
                              void* d_out, int out_size, void* d_ws, size_t ws_size,
                              hipStream_t stream) {
    const float* x   = (const float*)d_in[0];
    const int*   ei  = (const int*)d_in[1];
    const float* Wl1 = (const float*)d_in[2];
    const float* Wr1 = (const float*)d_in[3];
    const float* b1  = (const float*)d_in[4];
    const float* Wl2 = (const float*)d_in[5];
    const float* Wr2 = (const float*)d_in[6];
    const float* b2  = (const float*)d_in[7];
    float* out = (float*)d_out;

    u32* ws32    = (u32*)d_ws;
    u32* bar     = ws32;                        // [16]
    u32* histG   = ws32 + 64;                   // [36015]
    u32* bsum    = ws32 + 36096;                // [735]
    u32* sortedE = ws32 + 36864;                // [2.5M]
    u32* PART    = ws32 + 2536864 + 32;         // [735*6144] = 18.1 MB
    u32* PART2   = PART + GRID * 3 * SBSZ;      // [735*4096] = 12.0 MB
    u64* ench2   = (u64*)(PART2 + GRID * 2 * SBSZ);   // [N] u64 (even u32 offset)
    float2* hrG  = (float2*)(ench2 + N_NODES);        // [N]
    float* degG  = (float*)(hrG + N_NODES);           // [N]
    // total ws use ~42.3 MB

    hipMemsetAsync(bar, 0, 64, stream);
    mega<<<GRID, 256, 0, stream>>>(x, ei, Wl1, Wr1, b1, Wl2, Wr2, b2,
                                   bar, histG, bsum, sortedE, PART, PART2,
                                   ench2, hrG, degG, out);
}

// Round 12
// 671.538 us; speedup vs baseline: 1.0169x; 1.0169x over previous
//
#include <hip/hip_runtime.h>

#define N_NODES 100000
#define N_EDGES 2500000
#define SBBITS 11
#define SBSZ 2048              // nodes per superbucket
#define NSB 49                 // ceil(N_NODES/2048)
#define M 15                   // agg slices per superbucket
#define GRID (NSB * M)         // 735 blocks; <= 256 CUs * 3 blocks/CU = 768 co-resident
#define EPB 3402               // ceil(N_EDGES/GRID)
#define TOT (NSB * GRID)       // 36015 (k-major, block-minor counts)
#define CHK 49                 // TOT/GRID exactly

// pass-1 fixed point: (x+16)*2^16; u32 sum ok; signed debias via (int) [R6-validated]
// pass-2 fixed point: (h2+2048)*2^12; signed debias via (int)          [R6-validated]

typedef unsigned int u32;
typedef unsigned long long u64;

// One-shot grid barrier (each slot used exactly once per launch).
// RELEASE: __threadfence() (agent scope) writes back dirty L2 before arrive.
// POLL: atomic RMW of 0 — RMWs execute at the memory-side coherence point,
// so they can NEVER be served from a stale local-XCD L2 line (the R10 bug:
// a relaxed atomic LOAD cached the line locally; increments from other XCDs
// were invisible until random eviction -> ~70 us/barrier).
// ACQUIRE: __threadfence() invalidates stale L2 lines after release observed.
__device__ __forceinline__ void gbar(u32* bar, int slot) {
    __syncthreads();
    if (threadIdx.x == 0) {
        __threadfence();
        __hip_atomic_fetch_add(&bar[slot], 1u, __ATOMIC_RELAXED,
                               __HIP_MEMORY_SCOPE_AGENT);
        while (__hip_atomic_fetch_add(&bar[slot], 0u, __ATOMIC_RELAXED,
                                      __HIP_MEMORY_SCOPE_AGENT) < GRID)
            __builtin_amdgcn_s_sleep(8);
        __threadfence();
    }
    __syncthreads();
}

__global__ __launch_bounds__(256, 3) void mega(
    const float* __restrict__ x, const int* __restrict__ ei,
    const float* __restrict__ Wl1, const float* __restrict__ Wr1,
    const float* __restrict__ b1, const float* __restrict__ Wl2,
    const float* __restrict__ Wr2, const float* __restrict__ b2,
    u32* bar, u32* __restrict__ histG, u32* __restrict__ bsum,
    u32* __restrict__ sortedE, u32* __restrict__ PART, u32* __restrict__ PART2,
    u64* __restrict__ ench2, float2* __restrict__ hrG, float* __restrict__ degG,
    float* __restrict__ out)
{
    __shared__ u32 sm[3 * SBSZ];   // 24 KB, reused per phase
    const int t = threadIdx.x, b = blockIdx.x;

    // ---------------- P1: per-(sb, block) histogram ----------------
    for (int k = t; k < NSB * 8; k += 256) sm[k] = 0;
    __syncthreads();
    {
        int e0 = b * EPB, e1 = min(e0 + EPB, N_EDGES);
        int r = t & 7;
        for (int e = e0 + t; e < e1; e += 256) {
            u32 dst = (u32)ei[N_EDGES + e];
            atomicAdd(&sm[(dst >> SBBITS) * 8 + r], 1u);
        }
    }
    __syncthreads();
    for (int k = t; k < NSB; k += 256) {
        u32 s = 0;
#pragma unroll
        for (int j = 0; j < 8; ++j) s += sm[k * 8 + j];
        histG[k * GRID + b] = s;
    }
    gbar(bar, 0);

    // ---------------- P2: local scan of this block's 49-chunk ----------------
    u32 excl = 0;
    {
        u32 v = (t < CHK) ? histG[b * CHK + t] : 0u;
        if (t < 64) sm[t] = v;
        __syncthreads();
        for (int off = 1; off < 64; off <<= 1) {
            u32 a = (t >= off && t < 64) ? sm[t - off] : 0u;
            __syncthreads();
            if (t < 64) sm[t] += a;
            __syncthreads();
        }
        if (t < CHK) excl = (t == 0) ? 0u : sm[t - 1];
        if (t == 0) bsum[b] = sm[CHK - 1];
        __syncthreads();
    }
    gbar(bar, 1);

    // ---------------- P3: global base (masked sum of bsum[<b]) + writeback ----
    {
        u32 part = 0;
        for (int j = t; j < b; j += 256) part += bsum[j];
        sm[t] = part;
        __syncthreads();
        for (int off = 128; off > 0; off >>= 1) {
            if (t < off) sm[t] += sm[t + off];
            __syncthreads();
        }
        u32 base = sm[0];
        __syncthreads();
        if (t < CHK) histG[b * CHK + t] = base + excl;
    }
    gbar(bar, 2);

    // ---------------- P4: scatter into superbucket order ----------------
    {
        if (t < NSB) sm[t] = histG[t * GRID + b];
        __syncthreads();
        int e0 = b * EPB, e1 = min(e0 + EPB, N_EDGES);
        for (int e = e0 + t; e < e1; e += 256) {
            u32 src = (u32)ei[e];
            u32 dst = (u32)ei[N_EDGES + e];
            u32 slot = atomicAdd(&sm[dst >> SBBITS], 1u);
            sortedE[slot] = ((dst & (SBSZ - 1u)) << 17) | src;
        }
    }
    gbar(bar, 3);

    // ---------------- P5: agg1 (LDS fixed-point partials of x) ----------------
    {
        u32 sb = (u32)b / M, m = (u32)b % M;
        for (int j = t; j < 3 * SBSZ; j += 256) sm[j] = 0;
        __syncthreads();
        u32 s0 = histG[sb * GRID];
        u32 s1 = (sb + 1 < NSB) ? histG[(sb + 1) * GRID] : N_EDGES;
        u32 len = s1 - s0;
        u32 a0 = s0 + len * m / M, a1 = s0 + len * (m + 1) / M;
        const float2* x2 = (const float2*)x;
        u32 idx = a0 + t;
        while (idx + 256 < a1) {
            u32 p0 = sortedE[idx], p1 = sortedE[idx + 256];
            float2 v0 = x2[p0 & 0x1FFFFu];
            float2 v1 = x2[p1 & 0x1FFFFu];
            u32 l0 = p0 >> 17, l1 = p1 >> 17;
            atomicAdd(&sm[l0], 1u);
            atomicAdd(&sm[SBSZ + l0], (u32)((v0.x + 16.0f) * 65536.0f + 0.5f));
            atomicAdd(&sm[2 * SBSZ + l0], (u32)((v0.y + 16.0f) * 65536.0f + 0.5f));
            atomicAdd(&sm[l1], 1u);
            atomicAdd(&sm[SBSZ + l1], (u32)((v1.x + 16.0f) * 65536.0f + 0.5f));
            atomicAdd(&sm[2 * SBSZ + l1], (u32)((v1.y + 16.0f) * 65536.0f + 0.5f));
            idx += 512;
        }
        while (idx < a1) {
            u32 p = sortedE[idx];
            float2 v = x2[p & 0x1FFFFu];
            u32 l = p >> 17;
            atomicAdd(&sm[l], 1u);
            atomicAdd(&sm[SBSZ + l], (u32)((v.x + 16.0f) * 65536.0f + 0.5f));
            atomicAdd(&sm[2 * SBSZ + l], (u32)((v.y + 16.0f) * 65536.0f + 0.5f));
            idx += 256;
        }
        __syncthreads();
        u32 base = (u32)b * (3 * SBSZ);
        for (int j = t; j < 3 * SBSZ; j += 256) PART[base + j] = sm[j];
    }
    gbar(bar, 4);

    // ---------------- P6: reduce partials + node layer 1 ----------------
    {
        float* smf = (float*)sm;
        if (t < 64) {
            smf[t] = Wl1[t]; smf[64 + t] = Wr1[t];
            smf[128 + t] = Wl2[t]; smf[192 + t] = Wr2[t];
        }
        if (t >= 64 && t < 96) smf[256 + (t - 64)] = b1[t - 64];
        __syncthreads();
        int i = b * 137 + t;          // 735*137 = 100695 >= N
        if (t < 137 && i < N_NODES) {
            u32 sb2 = (u32)i >> SBBITS, j = (u32)i & (SBSZ - 1u);
            u32 cnt = 0, fx = 0, fy = 0;
#pragma unroll
            for (int mm = 0; mm < M; ++mm) {
                u32 bb = (sb2 * M + mm) * (3 * SBSZ);
                cnt += PART[bb + j];
                fx  += PART[bb + SBSZ + j];
                fy  += PART[bb + 2 * SBSZ + j];
            }
            float fc = (float)cnt;
            float dinv = 1.0f / fmaxf(fc, 1.0f);
            float ax = (float)(int)(fx - cnt * 1048576u) * (1.0f / 65536.0f) * dinv;
            float ay = (float)(int)(fy - cnt * 1048576u) * (1.0f / 65536.0f) * dinv;
            float2 xv = ((const float2*)x)[i];
            float h2a = 0.f, h2b = 0.f, hra = 0.f, hrb = 0.f;
#pragma unroll
            for (int f = 0; f < 32; ++f) {
                float h = ax * smf[f] + ay * smf[32 + f] +
                          xv.x * smf[64 + f] + xv.y * smf[96 + f] + smf[256 + f];
                h = fmaxf(h, 0.0f);
                h2a += h * smf[128 + 2 * f];
                h2b += h * smf[128 + 2 * f + 1];
                hra += h * smf[192 + 2 * f];
                hrb += h * smf[192 + 2 * f + 1];
            }
            u32 ex = (u32)((h2a + 2048.0f) * 4096.0f + 0.5f);
            u32 ey = (u32)((h2b + 2048.0f) * 4096.0f + 0.5f);
            ench2[i] = ((u64)ey << 32) | (u64)ex;
            hrG[i] = make_float2(hra, hrb);
            degG[i] = fc;
        }
    }
    gbar(bar, 5);

    // ---------------- P7: agg2 (LDS partials of encoded h2) ----------------
    {
        u32 sb = (u32)b / M, m = (u32)b % M;
        for (int j = t; j < 2 * SBSZ; j += 256) sm[j] = 0;
        __syncthreads();
        u32 s0 = histG[sb * GRID];
        u32 s1 = (sb + 1 < NSB) ? histG[(sb + 1) * GRID] : N_EDGES;
        u32 len = s1 - s0;
        u32 a0 = s0 + len * m / M, a1 = s0 + len * (m + 1) / M;
        u32 idx = a0 + t;
        while (idx + 256 < a1) {
            u32 p0 = sortedE[idx], p1 = sortedE[idx + 256];
            u64 e0 = ench2[p0 & 0x1FFFFu];
            u64 e1 = ench2[p1 & 0x1FFFFu];
            u32 l0 = p0 >> 17, l1 = p1 >> 17;
            atomicAdd(&sm[l0], (u32)e0);
            atomicAdd(&sm[SBSZ + l0], (u32)(e0 >> 32));
            atomicAdd(&sm[l1], (u32)e1);
            atomicAdd(&sm[SBSZ + l1], (u32)(e1 >> 32));
            idx += 512;
        }
        while (idx < a1) {
            u32 p = sortedE[idx];
            u64 e = ench2[p & 0x1FFFFu];
            u32 l = p >> 17;
            atomicAdd(&sm[l], (u32)e);
            atomicAdd(&sm[SBSZ + l], (u32)(e >> 32));
            idx += 256;
        }
        __syncthreads();
        u32 base = (u32)b * (2 * SBSZ);
        for (int j = t; j < 2 * SBSZ; j += 256) PART2[base + j] = sm[j];
    }
    gbar(bar, 6);

    // ---------------- P8: reduce + node layer 2 + log_softmax ----------------
    {
        int i = b * 137 + t;
        if (t < 137 && i < N_NODES) {
            u32 sb2 = (u32)i >> SBBITS, j = (u32)i & (SBSZ - 1u);
            u32 gx = 0, gy = 0;
#pragma unroll
            for (int mm = 0; mm < M; ++mm) {
                u32 bb = (sb2 * M + mm) * (2 * SBSZ);
                gx += PART2[bb + j];
                gy += PART2[bb + SBSZ + j];
            }
            float fc = degG[i];
            u32 c = (u32)fc;
            float dinv = 1.0f / fmaxf(fc, 1.0f);
            float sx = (float)(int)(gx - c * 8388608u) * (1.0f / 4096.0f) * dinv;
            float sy = (float)(int)(gy - c * 8388608u) * (1.0f / 4096.0f) * dinv;
            float2 hv = hrG[i];
            float o0 = sx + hv.x + b2[0];
            float o1 = sy + hv.y + b2[1];
            float mx = fmaxf(o0, o1);
            float e0 = expf(o0 - mx);
            float e1 = expf(o1 - mx);
            float lse = logf(e0 + e1);
            ((float2*)out)[i] = make_float2(o0 - mx - lse, o1 - mx - lse);
        }
    }
}

extern "C" void kernel_launch(void* const* d_in, const int* in_sizes, int n_in,
                              void* d_out, int out_size, void* d_ws, size_t ws_size,
                              hipStream_t stream) {
    const float* x   = (const float*)d_in[0];
    const int*   ei  = (const int*)d_in[1];
    const float* Wl1 = (const float*)d_in[2];
    const float* Wr1 = (const float*)d_in[3];
    const float* b1  = (const float*)d_in[4];
    const float* Wl2 = (const float*)d_in[5];
    const float* Wr2 = (const float*)d_in[6];
    const float* b2  = (const float*)d_in[7];
    float* out = (float*)d_out;

    u32* ws32    = (u32*)d_ws;
    u32* bar     = ws32;                        // [16]
    u32* histG   = ws32 + 64;                   // [36015]
    u32* bsum    = ws32 + 36096;                // [735]
    u32* sortedE = ws32 + 36864;                // [2.5M]
    u32* PART    = ws32 + 2536864 + 32;         // [735*6144] = 18.1 MB
    u32* PART2   = PART + GRID * 3 * SBSZ;      // [735*4096] = 12.0 MB
    u64* ench2   = (u64*)(PART2 + GRID * 2 * SBSZ);   // [N] u64 (even u32 offset)
    float2* hrG  = (float2*)(ench2 + N_NODES);        // [N]
    float* degG  = (float*)(hrG + N_NODES);           // [N]
    // total ws use ~42.3 MB

    hipMemsetAsync(bar, 0, 64, stream);
    mega<<<GRID, 256, 0, stream>>>(x, ei, Wl1, Wr1, b1, Wl2, Wr2, b2,
                                   bar, histG, bsum, sortedE, PART, PART2,
                                   ench2, hrG, degG, out);
}